// Round 13
// baseline (3434.543 us; speedup 1.0000x reference)
//
#include <hip/hip_runtime.h>
#include <hip/hip_bf16.h>
#include <stdint.h>

// Problem constants: NA=NT=1024, A_DIM=E_DIM=128, L=128

typedef short bf16x8 __attribute__((ext_vector_type(8)));
typedef float f32x4  __attribute__((ext_vector_type(4)));

#define GLD16(g, l) __builtin_amdgcn_global_load_lds( \
    (const __attribute__((address_space(1))) void*)(uintptr_t)(g), \
    (__attribute__((address_space(3))) void*)(uintptr_t)(l), 16, 0, 0)

#define BF_LO(v) __uint_as_float((v) << 16)
#define BF_HI(v) __uint_as_float((v) & 0xffff0000u)

static __device__ __forceinline__ uint32_t pk2(float lo, float hi) {
    __hip_bfloat16 h0 = __float2bfloat16(lo), h1 = __float2bfloat16(hi);
    return ((uint32_t)(*(uint16_t*)&h1) << 16) | (uint32_t)(*(uint16_t*)&h0);
}

// ---------------- fused prep: inputs transpose + weight transposes + init + ticket zero ----------------
// b < 1024         : transpose inputs tile
// 1024 <= b < 5120 : per-label 128x128 weight transpose + bf16 cast
// 5120 <= b < 7168 : init output + bf16 mirrors
// 7168 <= b < 7184 : zero ticket arrays (4 x 1024 ints)
__global__ __launch_bounds__(256) void prep_kernel(const int* __restrict__ in,
                                                   int* __restrict__ inT,
                                                   const float* __restrict__ W2,
                                                   const float* __restrict__ W1,
                                                   uint16_t* __restrict__ O2T,
                                                   uint16_t* __restrict__ O1T,
                                                   const float* __restrict__ fa,
                                                   const float* __restrict__ ft,
                                                   float* __restrict__ out,
                                                   uint16_t* __restrict__ srcAb,
                                                   uint16_t* __restrict__ srcTb,
                                                   int* __restrict__ tickets) {
    __shared__ float tile[32][33];
    int b = blockIdx.x;
    int tx = threadIdx.x & 31, ty = threadIdx.x >> 5;

    if (b < 1024) {                       // ---- transpose inputs ----
        int tr = b >> 5, tc = b & 31;
        int r0 = tr * 32, c0 = tc * 32;
#pragma unroll
        for (int p = 0; p < 4; ++p)
            tile[ty + p * 8][tx] = __int_as_float(in[(size_t)(r0 + ty + p * 8) * 1024 + c0 + tx]);
        __syncthreads();
#pragma unroll
        for (int p = 0; p < 4; ++p) {
            int cc = ty + p * 8;
            inT[(size_t)(c0 + cc) * 1024 + r0 + tx] = __float_as_int(tile[tx][cc]);
        }
    } else if (b < 5120) {                // ---- weight transpose + cast ----
        int bb = b - 1024;
        const float* W = W2;
        uint16_t* O = O2T;
        if (bb >= 2048) { bb -= 2048; W = W1; O = O1T; }
        int l = bb >> 4, sub = bb & 15;
        int x0 = (sub >> 2) * 32, y0 = (sub & 3) * 32;
#pragma unroll
        for (int p = 0; p < 4; ++p)
            tile[ty + p * 8][tx] = W[(size_t)l * 16384 + (size_t)(x0 + ty + p * 8) * 128 + y0 + tx];
        __syncthreads();
#pragma unroll
        for (int p = 0; p < 4; ++p) {
            int yy = ty + p * 8;
            __hip_bfloat16 h = __float2bfloat16(tile[tx][yy]);
            O[(size_t)(l * 128 + y0 + yy) * 128 + x0 + tx] = *(uint16_t*)&h;
        }
    } else if (b < 7168) {                // ---- init output + mirrors ----
        int i = (b - 5120) * 256 + threadIdx.x;
        int r = i >> 8, c = i & 255;
        float v = 0.f;
        if (c < 128) {
            v = (r < 1024) ? fa[(size_t)r * 128 + c] : ft[(size_t)(r - 1024) * 128 + c];
            __hip_bfloat16 h = __float2bfloat16(v);
            if (r < 1024) srcAb[(size_t)r * 128 + c] = *(uint16_t*)&h;
            else          srcTb[(size_t)(r - 1024) * 128 + c] = *(uint16_t*)&h;
        }
        out[i] = v;
    } else {                              // ---- zero tickets ----
        tickets[(b - 7168) * 256 + threadIdx.x] = 0;
    }
}

// ---------------- proj: P[1024][16384] = src[1024][128] x WT[16384][128]^T (bf16, K=128) ----------------
// 8 waves (2x4), wave tile 64x32, swapped-operand MFMA -> C^T fragments.
__global__ __launch_bounds__(512, 2) void proj_kernel(const uint16_t* __restrict__ src,  // [1024][128]
                                                      const uint16_t* __restrict__ WT,   // [16384][128]
                                                      uint16_t* __restrict__ proj) {     // [1024][16384]
    __shared__ uint16_t At[128 * 128];   // 32 KiB, 16B-slot XOR-swizzled by row&15
    __shared__ uint16_t Bt[128 * 128];

    const int tid = threadIdx.x;
    const int lane = tid & 63, wv = tid >> 6;
    const int bid = blockIdx.x;
    const int mt = bid & 7;
    const int nt = bid >> 3;            // 0..127
    const int wr = wv >> 2, wc = wv & 3;

    const int rr = lane >> 4;           // 0..3
    const int sx16 = lane & 15;
#pragma unroll
    for (int g = 0; g < 4; ++g) {
        int row = wv * 16 + g * 4 + rr;
        int sx = sx16 ^ (row & 15);     // pre-swizzled source (involution)
        GLD16((const char*)src + ((size_t)(mt * 128 + row) * 128 + sx * 8) * 2,
              (char*)At + (wv * 16 + g * 4) * 256);
        GLD16((const char*)WT + ((size_t)(nt * 128 + row) * 128 + sx * 8) * 2,
              (char*)Bt + (wv * 16 + g * 4) * 256);
    }
    __syncthreads();   // drains GLD16 vmcnt

    f32x4 acc[4][2] = {};
    const int q = lane >> 4, rl = lane & 15;
#pragma unroll
    for (int kk = 0; kk < 4; ++kk) {
        bf16x8 af[4], bfr[2];
#pragma unroll
        for (int m = 0; m < 4; ++m) {
            int row = wr * 64 + m * 16 + rl;
            int sw = (kk * 4 + q) ^ (row & 15);
            af[m] = *(const bf16x8*)((const char*)At + row * 256 + sw * 16);
        }
#pragma unroll
        for (int n = 0; n < 2; ++n) {
            int row = wc * 32 + n * 16 + rl;
            int sw = (kk * 4 + q) ^ (row & 15);
            bfr[n] = *(const bf16x8*)((const char*)Bt + row * 256 + sw * 16);
        }
#pragma unroll
        for (int m = 0; m < 4; ++m)
#pragma unroll
            for (int n = 0; n < 2; ++n)   // swapped operands -> D = C^T fragment
                acc[m][n] = __builtin_amdgcn_mfma_f32_16x16x32_bf16(bfr[n], af[m], acc[m][n], 0, 0, 0);
    }

    // C^T frag: col(lane&15) = m-space, row(q*4+reg) = n-space -> regs are 4 consecutive n.
#pragma unroll
    for (int m = 0; m < 4; ++m)
#pragma unroll
        for (int n = 0; n < 2; ++n) {
            int mrow = mt * 128 + wr * 64 + m * 16 + rl;
            int ncol = nt * 128 + wc * 32 + n * 16 + q * 4;
            uint2 pk;
            pk.x = pk2(acc[m][n][0], acc[m][n][1]);
            pk.y = pk2(acc[m][n][2], acc[m][n][3]);
            *(uint2*)(proj + (size_t)mrow * 16384 + ncol) = pk;
        }
}

// ---------------- gather + fused last-block reduce/state/mirror ----------------
// Block (j, ts), bid = j*8+ts. Each block writes partial[j][ts]; the 8th arriving block
// for j re-reads the 8 partials (agent-scope atomic loads, fixed-order sum) and updates
// state + bf16 mirror. Deterministic; no waiting; tickets zeroed per launch by prep.
__global__ __launch_bounds__(256, 8) void gather_phase_kernel(
    const int* __restrict__ labels,     // [1024][1024]
    const uint32_t* __restrict__ proj,  // [1024][8192] u32 view
    float* __restrict__ partial,        // [1024][8][128]
    int* __restrict__ ticket,           // [1024], zeroed
    float* __restrict__ state,          // [1024][256] (cols 0..127 live)
    uint16_t* __restrict__ mirror)      // [1024][128]
{
    __shared__ uint16_t lab16[128];
    __shared__ float red[4][128];
    __shared__ int lastflag;
    const int bid = blockIdx.x;
    const int j = bid >> 3, ts = bid & 7;
    const int tid = threadIdx.x;
    const int lane = tid & 63, wv = tid >> 6;

    if (tid < 128) lab16[tid] = (uint16_t)labels[(size_t)j * 1024 + ts * 128 + tid];
    __syncthreads();

    const uint32_t lane_u = (uint32_t)lane;
    const uint32_t* tb = proj + (size_t)(ts * 128 + wv * 32) * 8192 + lane_u;
    float a0 = 0.f, a1 = 0.f, b0 = 0.f, b1 = 0.f;
    float c0 = 0.f, c1 = 0.f, d0 = 0.f, d1 = 0.f;

#pragma unroll 1
    for (int i = 0; i < 32; i += 16) {
        int L[16];
#pragma unroll
        for (int g = 0; g < 4; ++g) {
            ushort4 q = *(const ushort4*)&lab16[wv * 32 + i + g * 4];   // wave-uniform ds_read_b64
            L[g * 4 + 0] = __builtin_amdgcn_readfirstlane((int)q.x);
            L[g * 4 + 1] = __builtin_amdgcn_readfirstlane((int)q.y);
            L[g * 4 + 2] = __builtin_amdgcn_readfirstlane((int)q.z);
            L[g * 4 + 3] = __builtin_amdgcn_readfirstlane((int)q.w);
        }
        uint32_t v[16];
#pragma unroll
        for (int e = 0; e < 16; ++e)     // scalar offsets -> saddr loads, 16 in flight
            v[e] = tb[(uint32_t)(i + e) * 8192u + (uint32_t)L[e] * 64u];

        a0 += BF_LO(v[0]) + BF_LO(v[1]) + BF_LO(v[2]) + BF_LO(v[3]);
        a1 += BF_HI(v[0]) + BF_HI(v[1]) + BF_HI(v[2]) + BF_HI(v[3]);
        b0 += BF_LO(v[4]) + BF_LO(v[5]) + BF_LO(v[6]) + BF_LO(v[7]);
        b1 += BF_HI(v[4]) + BF_HI(v[5]) + BF_HI(v[6]) + BF_HI(v[7]);
        c0 += BF_LO(v[8]) + BF_LO(v[9]) + BF_LO(v[10]) + BF_LO(v[11]);
        c1 += BF_HI(v[8]) + BF_HI(v[9]) + BF_HI(v[10]) + BF_HI(v[11]);
        d0 += BF_LO(v[12]) + BF_LO(v[13]) + BF_LO(v[14]) + BF_LO(v[15]);
        d1 += BF_HI(v[12]) + BF_HI(v[13]) + BF_HI(v[14]) + BF_HI(v[15]);
    }
    float2 pr;
    pr.x = (a0 + b0) + (c0 + d0);
    pr.y = (a1 + b1) + (c1 + d1);
    *(float2*)&red[wv][lane * 2] = pr;
    __syncthreads();

    if (tid < 128) {
        float s = (red[0][tid] + red[1][tid]) + (red[2][tid] + red[3][tid]);
        partial[((size_t)j * 8 + ts) * 128 + tid] = s;
    }
    __threadfence();          // release: partial visible at agent scope
    __syncthreads();          // whole block done fencing before the ticket bump
    if (tid == 0) lastflag = (atomicAdd(&ticket[j], 1) == 7);
    __syncthreads();

    if (lastflag) {
        __threadfence();      // acquire side
        if (tid < 128) {
            const float* p = partial + (size_t)j * 1024 + tid;
            float s0 = __hip_atomic_load(p + 0,   __ATOMIC_RELAXED, __HIP_MEMORY_SCOPE_AGENT);
            float s1 = __hip_atomic_load(p + 128, __ATOMIC_RELAXED, __HIP_MEMORY_SCOPE_AGENT);
            float s2 = __hip_atomic_load(p + 256, __ATOMIC_RELAXED, __HIP_MEMORY_SCOPE_AGENT);
            float s3 = __hip_atomic_load(p + 384, __ATOMIC_RELAXED, __HIP_MEMORY_SCOPE_AGENT);
            float s4 = __hip_atomic_load(p + 512, __ATOMIC_RELAXED, __HIP_MEMORY_SCOPE_AGENT);
            float s5 = __hip_atomic_load(p + 640, __ATOMIC_RELAXED, __HIP_MEMORY_SCOPE_AGENT);
            float s6 = __hip_atomic_load(p + 768, __ATOMIC_RELAXED, __HIP_MEMORY_SCOPE_AGENT);
            float s7 = __hip_atomic_load(p + 896, __ATOMIC_RELAXED, __HIP_MEMORY_SCOPE_AGENT);
            float s = ((s0 + s1) + (s2 + s3)) + ((s4 + s5) + (s6 + s7));   // same tree as before
            float v = state[(size_t)j * 256 + tid] + s;
            state[(size_t)j * 256 + tid] = v;
            __hip_bfloat16 h = __float2bfloat16(v);
            mirror[(size_t)j * 128 + tid] = *(uint16_t*)&h;
        }
    }
}

extern "C" void kernel_launch(void* const* d_in, const int* in_sizes, int n_in,
                              void* d_out, int out_size, void* d_ws, size_t ws_size,
                              hipStream_t stream) {
    const int*   inputs  = (const int*)d_in[0];
    const float* first_a = (const float*)d_in[1];
    const float* first_t = (const float*)d_in[2];
    const float* Awij    = (const float*)d_in[3];
    const float* Awij2   = (const float*)d_in[4];
    float* out = (float*)d_out;

    // workspace layout (52 MiB total)
    char* w = (char*)d_ws;
    int*      inputsT = (int*)(w);                      // 4 MiB
    uint16_t* W2T     = (uint16_t*)(w + (4u << 20));    // 4 MiB  [(l,a)][e]
    uint16_t* W1T     = (uint16_t*)(w + (8u << 20));    // 4 MiB  [(l,e)][a]
    uint16_t* srcAb   = (uint16_t*)(w + (12u << 20));   // 256 KiB bf16 mirror of stateA
    uint16_t* srcTb   = (uint16_t*)(w + (12u << 20) + (1u << 19)); // 256 KiB mirror of stateT
    float*    partial = (float*)(w + (13u << 20));      // 4 MiB  [1024][8][128]
    int*      tickets = (int*)(w + (17u << 20));        // 16 KiB (4 arrays of 1024)
    uint16_t* proj16  = (uint16_t*)(w + (20u << 20));   // 32 MiB [1024][16384] bf16
    if (ws_size < (52u << 20)) return;

    float* stateA = out;                 // [1024][256], cols 0..127 live
    float* stateT = out + 1024 * 256;    // [1024][256], cols 0..127 live

    prep_kernel<<<7184, 256, 0, stream>>>(inputs, inputsT, Awij2, Awij, W2T, W1T,
                                          first_a, first_t, out, srcAb, srcTb, tickets);

    for (int s = 0; s < 2; ++s) {
        // Phase A: t_proj = t_mirror x W2T^T; a[j] += sum_t t_proj[t, inputs[j,t], :]
        proj_kernel<<<1024, 512, 0, stream>>>(srcTb, W2T, proj16);
        gather_phase_kernel<<<8192, 256, 0, stream>>>(inputs, (const uint32_t*)proj16, partial,
                                                      tickets + (s * 2 + 0) * 1024, stateA, srcAb);
        // Phase T: a_proj = a_mirror x W1T^T; t[k] += sum_j a_proj[j, inputs[j,k], :]
        proj_kernel<<<1024, 512, 0, stream>>>(srcAb, W1T, proj16);
        gather_phase_kernel<<<8192, 256, 0, stream>>>(inputsT, (const uint32_t*)proj16, partial,
                                                      tickets + (s * 2 + 1) * 1024, stateT, srcTb);
    }
}

// Round 14
// 179.490 us; speedup vs baseline: 19.1350x; 19.1350x over previous
//
#include <hip/hip_runtime.h>
#include <hip/hip_bf16.h>
#include <stdint.h>

// Problem constants: NA=NT=1024, A_DIM=E_DIM=128, L=128

typedef short bf16x8 __attribute__((ext_vector_type(8)));
typedef float f32x4  __attribute__((ext_vector_type(4)));

#define GLD16(g, l) __builtin_amdgcn_global_load_lds( \
    (const __attribute__((address_space(1))) void*)(uintptr_t)(g), \
    (__attribute__((address_space(3))) void*)(uintptr_t)(l), 16, 0, 0)

#define BF_LO(v) __uint_as_float((v) << 16)
#define BF_HI(v) __uint_as_float((v) & 0xffff0000u)

static __device__ __forceinline__ uint32_t pk2(float lo, float hi) {
    __hip_bfloat16 h0 = __float2bfloat16(lo), h1 = __float2bfloat16(hi);
    return ((uint32_t)(*(uint16_t*)&h1) << 16) | (uint32_t)(*(uint16_t*)&h0);
}

// ---------------- fused prep: inputs transpose + weight transposes + init + ticket zero ----------------
// b < 1024         : transpose inputs tile
// 1024 <= b < 5120 : per-label 128x128 weight transpose + bf16 cast
//                    W2T[(l*128+a)][e] = Awij2[l][e][a], W1T[(l*128+e)][a] = Awij[l][a][e]
// 5120 <= b < 7168 : init output + bf16 mirrors
// 7168 <= b < 7184 : zero ticket arrays (4 x 1024 ints)
__global__ __launch_bounds__(256) void prep_kernel(const int* __restrict__ in,
                                                   int* __restrict__ inT,
                                                   const float* __restrict__ W2,
                                                   const float* __restrict__ W1,
                                                   uint16_t* __restrict__ O2T,
                                                   uint16_t* __restrict__ O1T,
                                                   const float* __restrict__ fa,
                                                   const float* __restrict__ ft,
                                                   float* __restrict__ out,
                                                   uint16_t* __restrict__ srcAb,
                                                   uint16_t* __restrict__ srcTb,
                                                   int* __restrict__ tickets) {
    __shared__ float tile[32][33];
    int b = blockIdx.x;
    int tx = threadIdx.x & 31, ty = threadIdx.x >> 5;

    if (b < 1024) {                       // ---- transpose inputs ----
        int tr = b >> 5, tc = b & 31;
        int r0 = tr * 32, c0 = tc * 32;
#pragma unroll
        for (int p = 0; p < 4; ++p)
            tile[ty + p * 8][tx] = __int_as_float(in[(size_t)(r0 + ty + p * 8) * 1024 + c0 + tx]);
        __syncthreads();
#pragma unroll
        for (int p = 0; p < 4; ++p) {
            int cc = ty + p * 8;
            inT[(size_t)(c0 + cc) * 1024 + r0 + tx] = __float_as_int(tile[tx][cc]);
        }
    } else if (b < 5120) {                // ---- weight transpose + cast ----
        int bb = b - 1024;
        const float* W = W2;
        uint16_t* O = O2T;
        if (bb >= 2048) { bb -= 2048; W = W1; O = O1T; }
        int l = bb >> 4, sub = bb & 15;
        int x0 = (sub >> 2) * 32, y0 = (sub & 3) * 32;
#pragma unroll
        for (int p = 0; p < 4; ++p)
            tile[ty + p * 8][tx] = W[(size_t)l * 16384 + (size_t)(x0 + ty + p * 8) * 128 + y0 + tx];
        __syncthreads();
#pragma unroll
        for (int p = 0; p < 4; ++p) {
            int yy = ty + p * 8;
            __hip_bfloat16 h = __float2bfloat16(tile[tx][yy]);
            O[(size_t)(l * 128 + y0 + yy) * 128 + x0 + tx] = *(uint16_t*)&h;
        }
    } else if (b < 7168) {                // ---- init output + mirrors ----
        int i = (b - 5120) * 256 + threadIdx.x;
        int r = i >> 8, c = i & 255;
        float v = 0.f;
        if (c < 128) {
            v = (r < 1024) ? fa[(size_t)r * 128 + c] : ft[(size_t)(r - 1024) * 128 + c];
            __hip_bfloat16 h = __float2bfloat16(v);
            if (r < 1024) srcAb[(size_t)r * 128 + c] = *(uint16_t*)&h;
            else          srcTb[(size_t)(r - 1024) * 128 + c] = *(uint16_t*)&h;
        }
        out[i] = v;
    } else {                              // ---- zero tickets ----
        tickets[(b - 7168) * 256 + threadIdx.x] = 0;
    }
}

// ---------------- proj: P[1024][16384] = src[1024][128] x WT[16384][128]^T (bf16, K=128) ----------------
// 8 waves (2x4), wave tile 64x32, swapped-operand MFMA -> C^T fragments.
__global__ __launch_bounds__(512, 2) void proj_kernel(const uint16_t* __restrict__ src,  // [1024][128]
                                                      const uint16_t* __restrict__ WT,   // [16384][128]
                                                      uint16_t* __restrict__ proj) {     // [1024][16384]
    __shared__ uint16_t At[128 * 128];   // 32 KiB, 16B-slot XOR-swizzled by row&15
    __shared__ uint16_t Bt[128 * 128];

    const int tid = threadIdx.x;
    const int lane = tid & 63, wv = tid >> 6;
    const int bid = blockIdx.x;
    const int mt = bid & 7;
    const int nt = bid >> 3;            // 0..127
    const int wr = wv >> 2, wc = wv & 3;

    const int rr = lane >> 4;           // 0..3
    const int sx16 = lane & 15;
#pragma unroll
    for (int g = 0; g < 4; ++g) {
        int row = wv * 16 + g * 4 + rr;
        int sx = sx16 ^ (row & 15);     // pre-swizzled source (involution)
        GLD16((const char*)src + ((size_t)(mt * 128 + row) * 128 + sx * 8) * 2,
              (char*)At + (wv * 16 + g * 4) * 256);
        GLD16((const char*)WT + ((size_t)(nt * 128 + row) * 128 + sx * 8) * 2,
              (char*)Bt + (wv * 16 + g * 4) * 256);
    }
    __syncthreads();   // drains GLD16 vmcnt

    f32x4 acc[4][2] = {};
    const int q = lane >> 4, rl = lane & 15;
#pragma unroll
    for (int kk = 0; kk < 4; ++kk) {
        bf16x8 af[4], bfr[2];
#pragma unroll
        for (int m = 0; m < 4; ++m) {
            int row = wr * 64 + m * 16 + rl;
            int sw = (kk * 4 + q) ^ (row & 15);
            af[m] = *(const bf16x8*)((const char*)At + row * 256 + sw * 16);
        }
#pragma unroll
        for (int n = 0; n < 2; ++n) {
            int row = wc * 32 + n * 16 + rl;
            int sw = (kk * 4 + q) ^ (row & 15);
            bfr[n] = *(const bf16x8*)((const char*)Bt + row * 256 + sw * 16);
        }
#pragma unroll
        for (int m = 0; m < 4; ++m)
#pragma unroll
            for (int n = 0; n < 2; ++n)   // swapped operands -> D = C^T fragment
                acc[m][n] = __builtin_amdgcn_mfma_f32_16x16x32_bf16(bfr[n], af[m], acc[m][n], 0, 0, 0);
    }

    // C^T frag: col(lane&15) = m-space, row(q*4+reg) = n-space -> regs are 4 consecutive n.
#pragma unroll
    for (int m = 0; m < 4; ++m)
#pragma unroll
        for (int n = 0; n < 2; ++n) {
            int mrow = mt * 128 + wr * 64 + m * 16 + rl;
            int ncol = nt * 128 + wc * 32 + n * 16 + q * 4;
            uint2 pk;
            pk.x = pk2(acc[m][n][0], acc[m][n][1]);
            pk.y = pk2(acc[m][n][2], acc[m][n][3]);
            *(uint2*)(proj + (size_t)mrow * 16384 + ncol) = pk;
        }
}

// ---------------- gather + fused last-block reduce/state/mirror (fence-free) ----------------
// Block (j, ts), bid = j*8+ts. Partial published via relaxed agent-scope atomic store
// (lands at device-coherent point; __syncthreads' vmcnt(0) drain completes it) then a
// relaxed agent-scope ticket fetch_add. The 8th block re-reads the 8 partials with
// relaxed agent-scope loads and does the fixed-order sum + state + mirror. NO fences
// (a __threadfence here would bulk-writeback L2 per block — round-13's 6x regression).
__global__ __launch_bounds__(256, 8) void gather_phase_kernel(
    const int* __restrict__ labels,     // [1024][1024]
    const uint32_t* __restrict__ proj,  // [1024][8192] u32 view
    float* __restrict__ partial,        // [1024][8][128]
    int* __restrict__ ticket,           // [1024], zeroed per launch
    float* __restrict__ state,          // [1024][256] (cols 0..127 live)
    uint16_t* __restrict__ mirror)      // [1024][128]
{
    __shared__ uint16_t lab16[128];
    __shared__ float red[4][128];
    __shared__ int lastflag;
    const int bid = blockIdx.x;
    const int j = bid >> 3, ts = bid & 7;
    const int tid = threadIdx.x;
    const int lane = tid & 63, wv = tid >> 6;

    if (tid < 128) lab16[tid] = (uint16_t)labels[(size_t)j * 1024 + ts * 128 + tid];
    __syncthreads();

    const uint32_t lane_u = (uint32_t)lane;
    const uint32_t* tb = proj + (size_t)(ts * 128 + wv * 32) * 8192 + lane_u;
    float a0 = 0.f, a1 = 0.f, b0 = 0.f, b1 = 0.f;
    float c0 = 0.f, c1 = 0.f, d0 = 0.f, d1 = 0.f;

#pragma unroll 1
    for (int i = 0; i < 32; i += 16) {
        int L[16];
#pragma unroll
        for (int g = 0; g < 4; ++g) {
            ushort4 q = *(const ushort4*)&lab16[wv * 32 + i + g * 4];   // wave-uniform ds_read_b64
            L[g * 4 + 0] = __builtin_amdgcn_readfirstlane((int)q.x);
            L[g * 4 + 1] = __builtin_amdgcn_readfirstlane((int)q.y);
            L[g * 4 + 2] = __builtin_amdgcn_readfirstlane((int)q.z);
            L[g * 4 + 3] = __builtin_amdgcn_readfirstlane((int)q.w);
        }
        uint32_t v[16];
#pragma unroll
        for (int e = 0; e < 16; ++e)     // scalar offsets -> saddr loads, 16 in flight
            v[e] = tb[(uint32_t)(i + e) * 8192u + (uint32_t)L[e] * 64u];

        a0 += BF_LO(v[0]) + BF_LO(v[1]) + BF_LO(v[2]) + BF_LO(v[3]);
        a1 += BF_HI(v[0]) + BF_HI(v[1]) + BF_HI(v[2]) + BF_HI(v[3]);
        b0 += BF_LO(v[4]) + BF_LO(v[5]) + BF_LO(v[6]) + BF_LO(v[7]);
        b1 += BF_HI(v[4]) + BF_HI(v[5]) + BF_HI(v[6]) + BF_HI(v[7]);
        c0 += BF_LO(v[8]) + BF_LO(v[9]) + BF_LO(v[10]) + BF_LO(v[11]);
        c1 += BF_HI(v[8]) + BF_HI(v[9]) + BF_HI(v[10]) + BF_HI(v[11]);
        d0 += BF_LO(v[12]) + BF_LO(v[13]) + BF_LO(v[14]) + BF_LO(v[15]);
        d1 += BF_HI(v[12]) + BF_HI(v[13]) + BF_HI(v[14]) + BF_HI(v[15]);
    }
    float2 pr;
    pr.x = (a0 + b0) + (c0 + d0);
    pr.y = (a1 + b1) + (c1 + d1);
    *(float2*)&red[wv][lane * 2] = pr;
    __syncthreads();

    if (tid < 128) {
        float s = (red[0][tid] + red[1][tid]) + (red[2][tid] + red[3][tid]);
        __hip_atomic_store(&partial[((size_t)j * 8 + ts) * 128 + tid], s,
                           __ATOMIC_RELAXED, __HIP_MEMORY_SCOPE_AGENT);
    }
    __syncthreads();          // compiler drains vmcnt(0) -> partial at coherent point
    if (tid == 0)
        lastflag = (__hip_atomic_fetch_add(&ticket[j], 1, __ATOMIC_RELAXED,
                                           __HIP_MEMORY_SCOPE_AGENT) == 7);
    __syncthreads();

    if (lastflag && tid < 128) {
        const float* p = partial + (size_t)j * 1024 + tid;
        float s0 = __hip_atomic_load(p + 0,   __ATOMIC_RELAXED, __HIP_MEMORY_SCOPE_AGENT);
        float s1 = __hip_atomic_load(p + 128, __ATOMIC_RELAXED, __HIP_MEMORY_SCOPE_AGENT);
        float s2 = __hip_atomic_load(p + 256, __ATOMIC_RELAXED, __HIP_MEMORY_SCOPE_AGENT);
        float s3 = __hip_atomic_load(p + 384, __ATOMIC_RELAXED, __HIP_MEMORY_SCOPE_AGENT);
        float s4 = __hip_atomic_load(p + 512, __ATOMIC_RELAXED, __HIP_MEMORY_SCOPE_AGENT);
        float s5 = __hip_atomic_load(p + 640, __ATOMIC_RELAXED, __HIP_MEMORY_SCOPE_AGENT);
        float s6 = __hip_atomic_load(p + 768, __ATOMIC_RELAXED, __HIP_MEMORY_SCOPE_AGENT);
        float s7 = __hip_atomic_load(p + 896, __ATOMIC_RELAXED, __HIP_MEMORY_SCOPE_AGENT);
        float s = ((s0 + s1) + (s2 + s3)) + ((s4 + s5) + (s6 + s7));   // same tree as before
        float v = state[(size_t)j * 256 + tid] + s;
        state[(size_t)j * 256 + tid] = v;
        __hip_bfloat16 h = __float2bfloat16(v);
        mirror[(size_t)j * 128 + tid] = *(uint16_t*)&h;
    }
}

extern "C" void kernel_launch(void* const* d_in, const int* in_sizes, int n_in,
                              void* d_out, int out_size, void* d_ws, size_t ws_size,
                              hipStream_t stream) {
    const int*   inputs  = (const int*)d_in[0];
    const float* first_a = (const float*)d_in[1];
    const float* first_t = (const float*)d_in[2];
    const float* Awij    = (const float*)d_in[3];
    const float* Awij2   = (const float*)d_in[4];
    float* out = (float*)d_out;

    // workspace layout (52 MiB total)
    char* w = (char*)d_ws;
    int*      inputsT = (int*)(w);                      // 4 MiB
    uint16_t* W2T     = (uint16_t*)(w + (4u << 20));    // 4 MiB  [(l,a)][e]
    uint16_t* W1T     = (uint16_t*)(w + (8u << 20));    // 4 MiB  [(l,e)][a]
    uint16_t* srcAb   = (uint16_t*)(w + (12u << 20));   // 256 KiB bf16 mirror of stateA
    uint16_t* srcTb   = (uint16_t*)(w + (12u << 20) + (1u << 19)); // 256 KiB mirror of stateT
    float*    partial = (float*)(w + (13u << 20));      // 4 MiB  [1024][8][128]
    int*      tickets = (int*)(w + (17u << 20));        // 16 KiB (4 arrays of 1024)
    uint16_t* proj16  = (uint16_t*)(w + (20u << 20));   // 32 MiB [1024][16384] bf16
    if (ws_size < (52u << 20)) return;

    float* stateA = out;                 // [1024][256], cols 0..127 live
    float* stateT = out + 1024 * 256;    // [1024][256], cols 0..127 live

    prep_kernel<<<7184, 256, 0, stream>>>(inputs, inputsT, Awij2, Awij, W2T, W1T,
                                          first_a, first_t, out, srcAb, srcTb, tickets);

    for (int s = 0; s < 2; ++s) {
        // Phase A: t_proj = t_mirror x W2T^T; a[j] += sum_t t_proj[t, inputs[j,t], :]
        proj_kernel<<<1024, 512, 0, stream>>>(srcTb, W2T, proj16);
        gather_phase_kernel<<<8192, 256, 0, stream>>>(inputs, (const uint32_t*)proj16, partial,
                                                      tickets + (s * 2 + 0) * 1024, stateA, srcAb);
        // Phase T: a_proj = a_mirror x W1T^T; t[k] += sum_j a_proj[j, inputs[j,k], :]
        proj_kernel<<<1024, 512, 0, stream>>>(srcAb, W1T, proj16);
        gather_phase_kernel<<<8192, 256, 0, stream>>>(inputsT, (const uint32_t*)proj16, partial,
                                                      tickets + (s * 2 + 1) * 1024, stateT, srcTb);
    }
}

// Round 15
// 174.144 us; speedup vs baseline: 19.7224x; 1.0307x over previous
//
#include <hip/hip_runtime.h>
#include <hip/hip_bf16.h>
#include <stdint.h>

// Problem constants: NA=NT=1024, A_DIM=E_DIM=128, L=128

typedef short bf16x8 __attribute__((ext_vector_type(8)));
typedef float f32x4  __attribute__((ext_vector_type(4)));

#define GLD16(g, l) __builtin_amdgcn_global_load_lds( \
    (const __attribute__((address_space(1))) void*)(uintptr_t)(g), \
    (__attribute__((address_space(3))) void*)(uintptr_t)(l), 16, 0, 0)

#define BF_LO(v) __uint_as_float((v) << 16)
#define BF_HI(v) __uint_as_float((v) & 0xffff0000u)

static __device__ __forceinline__ uint32_t pk2(float lo, float hi) {
    __hip_bfloat16 h0 = __float2bfloat16(lo), h1 = __float2bfloat16(hi);
    return ((uint32_t)(*(uint16_t*)&h1) << 16) | (uint32_t)(*(uint16_t*)&h0);
}

// ---------------- fused prep: inputs transpose + weight transposes + init ----------------
// b < 1024         : transpose inputs tile
// 1024 <= b < 5120 : per-label 128x128 weight transpose + bf16 cast
//                    W2T[(l*128+a)][e] = Awij2[l][e][a], W1T[(l*128+e)][a] = Awij[l][a][e]
// 5120 <= b < 7168 : init output + bf16 mirrors
__global__ __launch_bounds__(256) void prep_kernel(const int* __restrict__ in,
                                                   int* __restrict__ inT,
                                                   const float* __restrict__ W2,
                                                   const float* __restrict__ W1,
                                                   uint16_t* __restrict__ O2T,
                                                   uint16_t* __restrict__ O1T,
                                                   const float* __restrict__ fa,
                                                   const float* __restrict__ ft,
                                                   float* __restrict__ out,
                                                   uint16_t* __restrict__ srcAb,
                                                   uint16_t* __restrict__ srcTb) {
    __shared__ float tile[32][33];
    int b = blockIdx.x;
    int tx = threadIdx.x & 31, ty = threadIdx.x >> 5;

    if (b < 1024) {                       // ---- transpose inputs ----
        int tr = b >> 5, tc = b & 31;
        int r0 = tr * 32, c0 = tc * 32;
#pragma unroll
        for (int p = 0; p < 4; ++p)
            tile[ty + p * 8][tx] = __int_as_float(in[(size_t)(r0 + ty + p * 8) * 1024 + c0 + tx]);
        __syncthreads();
#pragma unroll
        for (int p = 0; p < 4; ++p) {
            int cc = ty + p * 8;
            inT[(size_t)(c0 + cc) * 1024 + r0 + tx] = __float_as_int(tile[tx][cc]);
        }
    } else if (b < 5120) {                // ---- weight transpose + cast ----
        int bb = b - 1024;
        const float* W = W2;
        uint16_t* O = O2T;
        if (bb >= 2048) { bb -= 2048; W = W1; O = O1T; }
        int l = bb >> 4, sub = bb & 15;
        int x0 = (sub >> 2) * 32, y0 = (sub & 3) * 32;
#pragma unroll
        for (int p = 0; p < 4; ++p)
            tile[ty + p * 8][tx] = W[(size_t)l * 16384 + (size_t)(x0 + ty + p * 8) * 128 + y0 + tx];
        __syncthreads();
#pragma unroll
        for (int p = 0; p < 4; ++p) {
            int yy = ty + p * 8;
            __hip_bfloat16 h = __float2bfloat16(tile[tx][yy]);
            O[(size_t)(l * 128 + y0 + yy) * 128 + x0 + tx] = *(uint16_t*)&h;
        }
    } else {                              // ---- init output + mirrors ----
        int i = (b - 5120) * 256 + threadIdx.x;
        int r = i >> 8, c = i & 255;
        float v = 0.f;
        if (c < 128) {
            v = (r < 1024) ? fa[(size_t)r * 128 + c] : ft[(size_t)(r - 1024) * 128 + c];
            __hip_bfloat16 h = __float2bfloat16(v);
            if (r < 1024) srcAb[(size_t)r * 128 + c] = *(uint16_t*)&h;
            else          srcTb[(size_t)(r - 1024) * 128 + c] = *(uint16_t*)&h;
        }
        out[i] = v;
    }
}

// ---------------- proj: P[1024][16384] = src[1024][128] x WT[16384][128]^T (bf16, K=128) ----------------
// mt = bid&7: XCD x computes/writes the t-row-slab that gather on XCD x reads.
// 8 waves (2x4), wave tile 64x32, swapped-operand MFMA -> C^T fragments.
__global__ __launch_bounds__(512, 2) void proj_kernel(const uint16_t* __restrict__ src,  // [1024][128]
                                                      const uint16_t* __restrict__ WT,   // [16384][128]
                                                      uint16_t* __restrict__ proj) {     // [1024][16384]
    __shared__ uint16_t At[128 * 128];   // 32 KiB, 16B-slot XOR-swizzled by row&15
    __shared__ uint16_t Bt[128 * 128];

    const int tid = threadIdx.x;
    const int lane = tid & 63, wv = tid >> 6;
    const int bid = blockIdx.x;
    const int mt = bid & 7;
    const int nt = bid >> 3;            // 0..127
    const int wr = wv >> 2, wc = wv & 3;

    const int rr = lane >> 4;           // 0..3
    const int sx16 = lane & 15;
#pragma unroll
    for (int g = 0; g < 4; ++g) {
        int row = wv * 16 + g * 4 + rr;
        int sx = sx16 ^ (row & 15);     // pre-swizzled source (involution)
        GLD16((const char*)src + ((size_t)(mt * 128 + row) * 128 + sx * 8) * 2,
              (char*)At + (wv * 16 + g * 4) * 256);
        GLD16((const char*)WT + ((size_t)(nt * 128 + row) * 128 + sx * 8) * 2,
              (char*)Bt + (wv * 16 + g * 4) * 256);
    }
    __syncthreads();   // drains GLD16 vmcnt

    f32x4 acc[4][2] = {};
    const int q = lane >> 4, rl = lane & 15;
#pragma unroll
    for (int kk = 0; kk < 4; ++kk) {
        bf16x8 af[4], bfr[2];
#pragma unroll
        for (int m = 0; m < 4; ++m) {
            int row = wr * 64 + m * 16 + rl;
            int sw = (kk * 4 + q) ^ (row & 15);
            af[m] = *(const bf16x8*)((const char*)At + row * 256 + sw * 16);
        }
#pragma unroll
        for (int n = 0; n < 2; ++n) {
            int row = wc * 32 + n * 16 + rl;
            int sw = (kk * 4 + q) ^ (row & 15);
            bfr[n] = *(const bf16x8*)((const char*)Bt + row * 256 + sw * 16);
        }
#pragma unroll
        for (int m = 0; m < 4; ++m)
#pragma unroll
            for (int n = 0; n < 2; ++n)   // swapped operands -> D = C^T fragment
                acc[m][n] = __builtin_amdgcn_mfma_f32_16x16x32_bf16(bfr[n], af[m], acc[m][n], 0, 0, 0);
    }

    // C^T frag: col(lane&15) = m-space, row(q*4+reg) = n-space -> regs are 4 consecutive n.
#pragma unroll
    for (int m = 0; m < 4; ++m)
#pragma unroll
        for (int n = 0; n < 2; ++n) {
            int mrow = mt * 128 + wr * 64 + m * 16 + rl;
            int ncol = nt * 128 + wc * 32 + n * 16 + q * 4;
            uint2 pk;
            pk.x = pk2(acc[m][n][0], acc[m][n][1]);
            pk.y = pk2(acc[m][n][2], acc[m][n][3]);
            *(uint2*)(proj + (size_t)mrow * 16384 + ncol) = pk;
        }
}

// ---------------- gather partial: partial[j][ts] = sum_{t in 64-row sub-slice ts} proj[t, lab[j][t], :] ----------------
// 16 sub-slices of 64 rows (2 MiB each). bid = half*8192 + j*8 + x, ts = half*8 + x:
// XCD = bid%8 = x (slice affinity preserved), and all half=0 blocks dispatch before
// half=1 -> each XCD streams ONE 2-MiB sub-slice at a time (fits L2 with headroom).
__global__ __launch_bounds__(256, 8) void gather_partial_kernel(
    const int* __restrict__ labels,     // [1024][1024]
    const uint32_t* __restrict__ proj,  // [1024][8192] u32 view
    float* __restrict__ partial)        // [1024][16][128]
{
    __shared__ uint16_t lab16[64];
    __shared__ float red[4][128];
    const int bid = blockIdx.x;
    const int half = bid >> 13;         // 0..1
    const int rem = bid & 8191;
    const int j = rem >> 3;             // 0..1023
    const int ts = half * 8 + (rem & 7);// 0..15
    const int tid = threadIdx.x;
    const int lane = tid & 63, wv = tid >> 6;

    if (tid < 64) lab16[tid] = (uint16_t)labels[(size_t)j * 1024 + ts * 64 + tid];
    __syncthreads();

    const uint32_t lane_u = (uint32_t)lane;
    const uint32_t* tb = proj + (size_t)(ts * 64 + wv * 16) * 8192 + lane_u;
    float a0 = 0.f, a1 = 0.f, b0 = 0.f, b1 = 0.f;
    float c0 = 0.f, c1 = 0.f, d0 = 0.f, d1 = 0.f;

    {
        int L[16];
#pragma unroll
        for (int g = 0; g < 4; ++g) {
            ushort4 q = *(const ushort4*)&lab16[wv * 16 + g * 4];   // wave-uniform ds_read_b64
            L[g * 4 + 0] = __builtin_amdgcn_readfirstlane((int)q.x);
            L[g * 4 + 1] = __builtin_amdgcn_readfirstlane((int)q.y);
            L[g * 4 + 2] = __builtin_amdgcn_readfirstlane((int)q.z);
            L[g * 4 + 3] = __builtin_amdgcn_readfirstlane((int)q.w);
        }
        uint32_t v[16];
#pragma unroll
        for (int e = 0; e < 16; ++e)     // scalar offsets -> saddr loads, 16 in flight
            v[e] = tb[(uint32_t)e * 8192u + (uint32_t)L[e] * 64u];

        a0 += BF_LO(v[0]) + BF_LO(v[1]) + BF_LO(v[2]) + BF_LO(v[3]);
        a1 += BF_HI(v[0]) + BF_HI(v[1]) + BF_HI(v[2]) + BF_HI(v[3]);
        b0 += BF_LO(v[4]) + BF_LO(v[5]) + BF_LO(v[6]) + BF_LO(v[7]);
        b1 += BF_HI(v[4]) + BF_HI(v[5]) + BF_HI(v[6]) + BF_HI(v[7]);
        c0 += BF_LO(v[8]) + BF_LO(v[9]) + BF_LO(v[10]) + BF_LO(v[11]);
        c1 += BF_HI(v[8]) + BF_HI(v[9]) + BF_HI(v[10]) + BF_HI(v[11]);
        d0 += BF_LO(v[12]) + BF_LO(v[13]) + BF_LO(v[14]) + BF_LO(v[15]);
        d1 += BF_HI(v[12]) + BF_HI(v[13]) + BF_HI(v[14]) + BF_HI(v[15]);
    }
    float2 pr;
    pr.x = (a0 + b0) + (c0 + d0);
    pr.y = (a1 + b1) + (c1 + d1);
    *(float2*)&red[wv][lane * 2] = pr;
    __syncthreads();

    if (tid < 128) {
        float s = (red[0][tid] + red[1][tid]) + (red[2][tid] + red[3][tid]);
        partial[((size_t)j * 16 + ts) * 128 + tid] = s;
    }
}

// ---------------- reduce 16 slice-partials + update state + emit bf16 mirror ----------------
__global__ __launch_bounds__(256) void reduce_state_kernel(const float* __restrict__ partial,
                                                           float* __restrict__ state,
                                                           uint16_t* __restrict__ mirror) {
    int i = blockIdx.x * 256 + threadIdx.x;   // grid 512 -> 131072
    int j = i >> 7, c = i & 127;
    const float* p = partial + (size_t)j * 2048 + c;
    float s0 = (p[0] + p[128]) + (p[256] + p[384]);
    float s1 = (p[512] + p[640]) + (p[768] + p[896]);
    float s2 = (p[1024] + p[1152]) + (p[1280] + p[1408]);
    float s3 = (p[1536] + p[1664]) + (p[1792] + p[1920]);
    float v = state[(size_t)j * 256 + c] + ((s0 + s1) + (s2 + s3));
    state[(size_t)j * 256 + c] = v;
    __hip_bfloat16 h = __float2bfloat16(v);
    mirror[(size_t)j * 128 + c] = *(uint16_t*)&h;
}

extern "C" void kernel_launch(void* const* d_in, const int* in_sizes, int n_in,
                              void* d_out, int out_size, void* d_ws, size_t ws_size,
                              hipStream_t stream) {
    const int*   inputs  = (const int*)d_in[0];
    const float* first_a = (const float*)d_in[1];
    const float* first_t = (const float*)d_in[2];
    const float* Awij    = (const float*)d_in[3];
    const float* Awij2   = (const float*)d_in[4];
    float* out = (float*)d_out;

    // workspace layout (54 MiB total)
    char* w = (char*)d_ws;
    int*      inputsT = (int*)(w);                      // 4 MiB
    uint16_t* W2T     = (uint16_t*)(w + (4u << 20));    // 4 MiB  [(l,a)][e]
    uint16_t* W1T     = (uint16_t*)(w + (8u << 20));    // 4 MiB  [(l,e)][a]
    uint16_t* srcAb   = (uint16_t*)(w + (12u << 20));   // 256 KiB bf16 mirror of stateA
    uint16_t* srcTb   = (uint16_t*)(w + (12u << 20) + (1u << 19)); // 256 KiB mirror of stateT
    float*    partial = (float*)(w + (13u << 20));      // 8 MiB  [1024][16][128]
    uint16_t* proj16  = (uint16_t*)(w + (22u << 20));   // 32 MiB [1024][16384] bf16
    if (ws_size < (54u << 20)) return;

    float* stateA = out;                 // [1024][256], cols 0..127 live
    float* stateT = out + 1024 * 256;    // [1024][256], cols 0..127 live

    prep_kernel<<<7168, 256, 0, stream>>>(inputs, inputsT, Awij2, Awij, W2T, W1T,
                                          first_a, first_t, out, srcAb, srcTb);

    for (int s = 0; s < 2; ++s) {
        // Phase A: t_proj = t_mirror x W2T^T; a[j] += sum_t t_proj[t, inputs[j,t], :]
        proj_kernel<<<1024, 512, 0, stream>>>(srcTb, W2T, proj16);
        gather_partial_kernel<<<16384, 256, 0, stream>>>(inputs, (const uint32_t*)proj16, partial);
        reduce_state_kernel<<<512, 256, 0, stream>>>(partial, stateA, srcAb);
        // Phase T: a_proj = a_mirror x W1T^T; t[k] += sum_j a_proj[j, inputs[j,k], :]
        proj_kernel<<<1024, 512, 0, stream>>>(srcAb, W1T, proj16);
        gather_partial_kernel<<<16384, 256, 0, stream>>>(inputsT, (const uint32_t*)proj16, partial);
        reduce_state_kernel<<<512, 256, 0, stream>>>(partial, stateT, srcTb);
    }
}

// Round 16
// 168.178 us; speedup vs baseline: 20.4221x; 1.0355x over previous
//
#include <hip/hip_runtime.h>
#include <hip/hip_bf16.h>
#include <stdint.h>

// Problem constants: NA=NT=1024, A_DIM=E_DIM=128, L=128

typedef short bf16x8 __attribute__((ext_vector_type(8)));
typedef float f32x4  __attribute__((ext_vector_type(4)));

#define GLD16(g, l) __builtin_amdgcn_global_load_lds( \
    (const __attribute__((address_space(1))) void*)(uintptr_t)(g), \
    (__attribute__((address_space(3))) void*)(uintptr_t)(l), 16, 0, 0)

// v_dot2_f32_bf16: acc += v.lo*ones.lo + v.hi*ones.hi  (1 VALU instr)
#define DOT2(acc, val, ones) \
    asm("v_dot2_f32_bf16 %0, %1, %2, %0" : "+v"(acc) : "v"(val), "v"(ones))

static __device__ __forceinline__ uint32_t pk2(float lo, float hi) {
    __hip_bfloat16 h0 = __float2bfloat16(lo), h1 = __float2bfloat16(hi);
    return ((uint32_t)(*(uint16_t*)&h1) << 16) | (uint32_t)(*(uint16_t*)&h0);
}

// ---------------- fused prep: inputs transpose + weight transposes + init ----------------
// b < 1024         : transpose inputs tile
// 1024 <= b < 5120 : per-label 128x128 weight transpose + bf16 cast
//                    W2T[(l*128+a)][e] = Awij2[l][e][a], W1T[(l*128+e)][a] = Awij[l][a][e]
// 5120 <= b < 7168 : init output + bf16 mirrors
__global__ __launch_bounds__(256) void prep_kernel(const int* __restrict__ in,
                                                   int* __restrict__ inT,
                                                   const float* __restrict__ W2,
                                                   const float* __restrict__ W1,
                                                   uint16_t* __restrict__ O2T,
                                                   uint16_t* __restrict__ O1T,
                                                   const float* __restrict__ fa,
                                                   const float* __restrict__ ft,
                                                   float* __restrict__ out,
                                                   uint16_t* __restrict__ srcAb,
                                                   uint16_t* __restrict__ srcTb) {
    __shared__ float tile[32][33];
    int b = blockIdx.x;
    int tx = threadIdx.x & 31, ty = threadIdx.x >> 5;

    if (b < 1024) {                       // ---- transpose inputs ----
        int tr = b >> 5, tc = b & 31;
        int r0 = tr * 32, c0 = tc * 32;
#pragma unroll
        for (int p = 0; p < 4; ++p)
            tile[ty + p * 8][tx] = __int_as_float(in[(size_t)(r0 + ty + p * 8) * 1024 + c0 + tx]);
        __syncthreads();
#pragma unroll
        for (int p = 0; p < 4; ++p) {
            int cc = ty + p * 8;
            inT[(size_t)(c0 + cc) * 1024 + r0 + tx] = __float_as_int(tile[tx][cc]);
        }
    } else if (b < 5120) {                // ---- weight transpose + cast ----
        int bb = b - 1024;
        const float* W = W2;
        uint16_t* O = O2T;
        if (bb >= 2048) { bb -= 2048; W = W1; O = O1T; }
        int l = bb >> 4, sub = bb & 15;
        int x0 = (sub >> 2) * 32, y0 = (sub & 3) * 32;
#pragma unroll
        for (int p = 0; p < 4; ++p)
            tile[ty + p * 8][tx] = W[(size_t)l * 16384 + (size_t)(x0 + ty + p * 8) * 128 + y0 + tx];
        __syncthreads();
#pragma unroll
        for (int p = 0; p < 4; ++p) {
            int yy = ty + p * 8;
            __hip_bfloat16 h = __float2bfloat16(tile[tx][yy]);
            O[(size_t)(l * 128 + y0 + yy) * 128 + x0 + tx] = *(uint16_t*)&h;
        }
    } else {                              // ---- init output + mirrors ----
        int i = (b - 5120) * 256 + threadIdx.x;
        int r = i >> 8, c = i & 255;
        float v = 0.f;
        if (c < 128) {
            v = (r < 1024) ? fa[(size_t)r * 128 + c] : ft[(size_t)(r - 1024) * 128 + c];
            __hip_bfloat16 h = __float2bfloat16(v);
            if (r < 1024) srcAb[(size_t)r * 128 + c] = *(uint16_t*)&h;
            else          srcTb[(size_t)(r - 1024) * 128 + c] = *(uint16_t*)&h;
        }
        out[i] = v;
    }
}

// ---------------- proj: P[1024][16384] = src[1024][128] x WT[16384][128]^T (bf16, K=128) ----------------
// mt = bid&7: XCD x computes/writes the t-row-slab that gather on XCD x reads.
// 8 waves (2x4), wave tile 64x32, swapped-operand MFMA -> C^T fragments.
__global__ __launch_bounds__(512, 2) void proj_kernel(const uint16_t* __restrict__ src,  // [1024][128]
                                                      const uint16_t* __restrict__ WT,   // [16384][128]
                                                      uint16_t* __restrict__ proj) {     // [1024][16384]
    __shared__ uint16_t At[128 * 128];   // 32 KiB, 16B-slot XOR-swizzled by row&15
    __shared__ uint16_t Bt[128 * 128];

    const int tid = threadIdx.x;
    const int lane = tid & 63, wv = tid >> 6;
    const int bid = blockIdx.x;
    const int mt = bid & 7;
    const int nt = bid >> 3;            // 0..127
    const int wr = wv >> 2, wc = wv & 3;

    const int rr = lane >> 4;           // 0..3
    const int sx16 = lane & 15;
#pragma unroll
    for (int g = 0; g < 4; ++g) {
        int row = wv * 16 + g * 4 + rr;
        int sx = sx16 ^ (row & 15);     // pre-swizzled source (involution)
        GLD16((const char*)src + ((size_t)(mt * 128 + row) * 128 + sx * 8) * 2,
              (char*)At + (wv * 16 + g * 4) * 256);
        GLD16((const char*)WT + ((size_t)(nt * 128 + row) * 128 + sx * 8) * 2,
              (char*)Bt + (wv * 16 + g * 4) * 256);
    }
    __syncthreads();   // drains GLD16 vmcnt

    f32x4 acc[4][2] = {};
    const int q = lane >> 4, rl = lane & 15;
#pragma unroll
    for (int kk = 0; kk < 4; ++kk) {
        bf16x8 af[4], bfr[2];
#pragma unroll
        for (int m = 0; m < 4; ++m) {
            int row = wr * 64 + m * 16 + rl;
            int sw = (kk * 4 + q) ^ (row & 15);
            af[m] = *(const bf16x8*)((const char*)At + row * 256 + sw * 16);
        }
#pragma unroll
        for (int n = 0; n < 2; ++n) {
            int row = wc * 32 + n * 16 + rl;
            int sw = (kk * 4 + q) ^ (row & 15);
            bfr[n] = *(const bf16x8*)((const char*)Bt + row * 256 + sw * 16);
        }
#pragma unroll
        for (int m = 0; m < 4; ++m)
#pragma unroll
            for (int n = 0; n < 2; ++n)   // swapped operands -> D = C^T fragment
                acc[m][n] = __builtin_amdgcn_mfma_f32_16x16x32_bf16(bfr[n], af[m], acc[m][n], 0, 0, 0);
    }

    // C^T frag: col(lane&15) = m-space, row(q*4+reg) = n-space -> regs are 4 consecutive n.
#pragma unroll
    for (int m = 0; m < 4; ++m)
#pragma unroll
        for (int n = 0; n < 2; ++n) {
            int mrow = mt * 128 + wr * 64 + m * 16 + rl;
            int ncol = nt * 128 + wc * 32 + n * 16 + q * 4;
            uint2 pk;
            pk.x = pk2(acc[m][n][0], acc[m][n][1]);
            pk.y = pk2(acc[m][n][2], acc[m][n][3]);
            *(uint2*)(proj + (size_t)mrow * 16384 + ncol) = pk;
        }
}

// ---------------- gather partial: partial[j][ts] = sum_{t in slice ts} proj[t, lab[j][t], :] ----------------
// Block (j, ts), bid = j*8+ts -> XCD ts reads its own 4 MiB slice. Labels wave-uniform ->
// readfirstlane + saddr loads, 16 in flight. Channel extract+accumulate via v_dot2_f32_bf16
// (1 instr per channel-acc instead of unpack+add): 10 -> 6 VALU-cycles per edge.
__global__ __launch_bounds__(256, 8) void gather_partial_kernel(
    const int* __restrict__ labels,     // [1024][1024]
    const uint32_t* __restrict__ proj,  // [1024][8192] u32 view
    float* __restrict__ partial)        // [1024][8][128]
{
    __shared__ uint16_t lab16[128];
    __shared__ float red[4][128];
    const int bid = blockIdx.x;
    const int j = bid >> 3, ts = bid & 7;
    const int tid = threadIdx.x;
    const int lane = tid & 63, wv = tid >> 6;

    if (tid < 128) lab16[tid] = (uint16_t)labels[(size_t)j * 1024 + ts * 128 + tid];
    __syncthreads();

    const uint32_t lane_u = (uint32_t)lane;
    const uint32_t* tb = proj + (size_t)(ts * 128 + wv * 32) * 8192 + lane_u;
    const uint32_t onesL = 0x00003F80u;  // (bf16 1.0, bf16 0.0) -> selects LOW channel
    const uint32_t onesH = 0x3F800000u;  // (bf16 0.0, bf16 1.0) -> selects HIGH channel
    float a0 = 0.f, a1 = 0.f, b0 = 0.f, b1 = 0.f;
    float c0 = 0.f, c1 = 0.f, d0 = 0.f, d1 = 0.f;

#pragma unroll 1
    for (int i = 0; i < 32; i += 16) {
        int L[16];
#pragma unroll
        for (int g = 0; g < 4; ++g) {
            ushort4 q = *(const ushort4*)&lab16[wv * 32 + i + g * 4];   // wave-uniform ds_read_b64
            L[g * 4 + 0] = __builtin_amdgcn_readfirstlane((int)q.x);
            L[g * 4 + 1] = __builtin_amdgcn_readfirstlane((int)q.y);
            L[g * 4 + 2] = __builtin_amdgcn_readfirstlane((int)q.z);
            L[g * 4 + 3] = __builtin_amdgcn_readfirstlane((int)q.w);
        }
        uint32_t v[16];
#pragma unroll
        for (int e = 0; e < 16; ++e)     // scalar offsets -> saddr loads, 16 in flight
            v[e] = tb[(uint32_t)(i + e) * 8192u + (uint32_t)L[e] * 64u];

        DOT2(a0, v[0], onesL);  DOT2(a1, v[0], onesH);
        DOT2(a0, v[1], onesL);  DOT2(a1, v[1], onesH);
        DOT2(a0, v[2], onesL);  DOT2(a1, v[2], onesH);
        DOT2(a0, v[3], onesL);  DOT2(a1, v[3], onesH);
        DOT2(b0, v[4], onesL);  DOT2(b1, v[4], onesH);
        DOT2(b0, v[5], onesL);  DOT2(b1, v[5], onesH);
        DOT2(b0, v[6], onesL);  DOT2(b1, v[6], onesH);
        DOT2(b0, v[7], onesL);  DOT2(b1, v[7], onesH);
        DOT2(c0, v[8], onesL);  DOT2(c1, v[8], onesH);
        DOT2(c0, v[9], onesL);  DOT2(c1, v[9], onesH);
        DOT2(c0, v[10], onesL); DOT2(c1, v[10], onesH);
        DOT2(c0, v[11], onesL); DOT2(c1, v[11], onesH);
        DOT2(d0, v[12], onesL); DOT2(d1, v[12], onesH);
        DOT2(d0, v[13], onesL); DOT2(d1, v[13], onesH);
        DOT2(d0, v[14], onesL); DOT2(d1, v[14], onesH);
        DOT2(d0, v[15], onesL); DOT2(d1, v[15], onesH);
    }
    float2 pr;
    pr.x = (a0 + b0) + (c0 + d0);
    pr.y = (a1 + b1) + (c1 + d1);
    *(float2*)&red[wv][lane * 2] = pr;
    __syncthreads();

    if (tid < 128) {
        float s = (red[0][tid] + red[1][tid]) + (red[2][tid] + red[3][tid]);
        partial[((size_t)j * 8 + ts) * 128 + tid] = s;
    }
}

// ---------------- reduce 8 slice-partials + update state + emit bf16 mirror ----------------
__global__ __launch_bounds__(256) void reduce_state_kernel(const float* __restrict__ partial,
                                                           float* __restrict__ state,
                                                           uint16_t* __restrict__ mirror) {
    int i = blockIdx.x * 256 + threadIdx.x;   // grid 512 -> 131072
    int j = i >> 7, c = i & 127;
    const float* p = partial + (size_t)j * 1024 + c;
    float s = ((p[0] + p[128]) + (p[256] + p[384])) + ((p[512] + p[640]) + (p[768] + p[896]));
    float v = state[(size_t)j * 256 + c] + s;
    state[(size_t)j * 256 + c] = v;
    __hip_bfloat16 h = __float2bfloat16(v);
    mirror[(size_t)j * 128 + c] = *(uint16_t*)&h;
}

extern "C" void kernel_launch(void* const* d_in, const int* in_sizes, int n_in,
                              void* d_out, int out_size, void* d_ws, size_t ws_size,
                              hipStream_t stream) {
    const int*   inputs  = (const int*)d_in[0];
    const float* first_a = (const float*)d_in[1];
    const float* first_t = (const float*)d_in[2];
    const float* Awij    = (const float*)d_in[3];
    const float* Awij2   = (const float*)d_in[4];
    float* out = (float*)d_out;

    // workspace layout (52 MiB total)
    char* w = (char*)d_ws;
    int*      inputsT = (int*)(w);                      // 4 MiB
    uint16_t* W2T     = (uint16_t*)(w + (4u << 20));    // 4 MiB  [(l,a)][e]
    uint16_t* W1T     = (uint16_t*)(w + (8u << 20));    // 4 MiB  [(l,e)][a]
    uint16_t* srcAb   = (uint16_t*)(w + (12u << 20));   // 256 KiB bf16 mirror of stateA
    uint16_t* srcTb   = (uint16_t*)(w + (12u << 20) + (1u << 19)); // 256 KiB mirror of stateT
    float*    partial = (float*)(w + (13u << 20));      // 4 MiB  [1024][8][128]
    uint16_t* proj16  = (uint16_t*)(w + (20u << 20));   // 32 MiB [1024][16384] bf16
    if (ws_size < (52u << 20)) return;

    float* stateA = out;                 // [1024][256], cols 0..127 live
    float* stateT = out + 1024 * 256;    // [1024][256], cols 0..127 live

    prep_kernel<<<7168, 256, 0, stream>>>(inputs, inputsT, Awij2, Awij, W2T, W1T,
                                          first_a, first_t, out, srcAb, srcTb);

    for (int s = 0; s < 2; ++s) {
        // Phase A: t_proj = t_mirror x W2T^T; a[j] += sum_t t_proj[t, inputs[j,t], :]
        proj_kernel<<<1024, 512, 0, stream>>>(srcTb, W2T, proj16);
        gather_partial_kernel<<<8192, 256, 0, stream>>>(inputs, (const uint32_t*)proj16, partial);
        reduce_state_kernel<<<512, 256, 0, stream>>>(partial, stateA, srcAb);
        // Phase T: a_proj = a_mirror x W1T^T; t[k] += sum_j a_proj[j, inputs[j,k], :]
        proj_kernel<<<1024, 512, 0, stream>>>(srcAb, W1T, proj16);
        gather_partial_kernel<<<8192, 256, 0, stream>>>(inputsT, (const uint32_t*)proj16, partial);
        reduce_state_kernel<<<512, 256, 0, stream>>>(partial, stateT, srcTb);
    }
}